// Round 1
// baseline (584.696 us; speedup 1.0000x reference)
//
#include <hip/hip_runtime.h>
#include <math.h>

#define BM 128
#define BN 128
#define BK 64

typedef _Float16 f16x8 __attribute__((ext_vector_type(8)));
typedef __attribute__((ext_vector_type(4))) float f32x4;

typedef const __attribute__((address_space(1))) void* gas_ptr;
typedef __attribute__((address_space(3))) void* las_ptr;

enum { OP_NONE = 0, OP_BIAS_GELU = 1, OP_BIAS = 2, OP_SCALE_MASK = 3 };

__device__ __forceinline__ unsigned short f2h(float f) {
    _Float16 h = (_Float16)f;  // RTNE
    unsigned short u;
    __builtin_memcpy(&u, &h, 2);
    return u;
}
__device__ __forceinline__ float h2f(unsigned short u) {
    _Float16 h;
    __builtin_memcpy(&h, &u, 2);
    return (float)h;
}

// tanh-form GELU via sigmoid: ~7 VALU instrs vs ~50 for libm erff.
// R6/R7 confirmed: absmax stays 0.03125 with this approximation.
__device__ __forceinline__ float fast_gelu(float x) {
    float x2 = x * x;
    float p  = x * (-1.5957691216f - 0.0713548164f * x2);  // = -2u
    float t  = __expf(p);                                  // e^{-2u}
    return x * __builtin_amdgcn_rcpf(1.0f + t);            // x * sigma(2u)
}

// ---------------------------------------------------------------------------
// 256x256-tile 8-phase GEMM (HK-schedule port, plain HIP) for the MLP GEMMs.
// 8 waves (2M x 4N), BK=64, 128 KiB LDS double-buffer, per-wave 128x64 out.
// K-loop: 8 phases per 2 K-tiles; each phase = {ds_read subtile || 1 half-tile
// global_load_lds} -> s_barrier -> lgkmcnt(0) -> setprio(1)+16 MFMA -> barrier.
// Counted vmcnt(4) ONLY at phases 4/8 (never 0 in-loop): keeps 2-3 half-tiles
// in flight across barriers (T3+T4). XOR chunk-swizzle (chunk ^ (row&7)) on
// both the pre-swizzled global source and the ds_read side (0 bank conflicts,
// carried over from the 128^2 kernel). Requires: M,N % 256 == 0, K % 128 == 0.
// ---------------------------------------------------------------------------
template <int EPI>
__global__ __launch_bounds__(512, 2) void gemm256(
    const unsigned short* __restrict__ A,
    const unsigned short* __restrict__ BT,
    unsigned short* __restrict__ Cw,
    const float* __restrict__ bias0,
    const float* __restrict__ bias1,
    const float* __restrict__ bias2,
    int M, int N, int K,
    long long sA, long long sB, long long sC)
{
    __shared__ __align__(16) unsigned short As[2 * 256 * 64];  // 64 KiB
    __shared__ __align__(16) unsigned short Bs[2 * 256 * 64];  // 64 KiB

    const int tid  = threadIdx.x;
    const int wave = tid >> 6;
    const int lane = tid & 63;

    const int bm = blockIdx.x * 256;
    const int bn = blockIdx.y * 256;
    const int z  = blockIdx.z;

    const unsigned short* Ab = A  + (long long)z * sA;
    const unsigned short* Bb = BT + (long long)z * sB;
    unsigned short*       Cb = Cw + (long long)z * sC;
    const float* bias = (z == 0) ? bias0 : (z == 1) ? bias1 : bias2;

    const int wm = (wave >> 2) * 128;  // 2 M-wave groups
    const int wn = (wave & 3) * 64;    // 4 N-wave groups

    const int srow = lane >> 3;              // 0..7: row within 8-row slab
    const int swzc = (lane & 7) ^ srow;      // pre-swizzled global chunk
    const int fr   = lane & 15;
    const int quad = lane >> 4;

    // per-lane staging sources (row = base + wave*8 + srow, col = swzc*8)
    const unsigned short* srcA = Ab + (long long)(bm + wave * 8 + srow) * K + swzc * 8;
    const unsigned short* srcB = Bb + (long long)(bn + wave * 8 + srow) * K + swzc * 8;

    const int NT = K >> 6;   // 64-wide K-tiles; even by contract
    const int NI = NT >> 1;

    f32x4 acc[8][4];
    #pragma unroll
    for (int i = 0; i < 8; i++)
        #pragma unroll
        for (int j = 0; j < 4; j++)
            acc[i][j] = (f32x4){0.f, 0.f, 0.f, 0.f};

// stage one half-tile (128 rows x 64 cols) of tile t, half h: 2 loads/thread.
// LDS dest is linear (wave-uniform base + lane*16); source pre-swizzled.
// t >= NT clamps the k-column to tile (t&1) (same buffer parity; value dead).
#define STG(src, lds, t, h)                                                    \
    {                                                                          \
        const int tc_ = ((t) < NT) ? (t) : ((t) & 1);                          \
        const int bs_ = ((t) & 1) * 16384;                                     \
        _Pragma("unroll")                                                      \
        for (int s_ = 0; s_ < 2; ++s_) {                                       \
            __builtin_amdgcn_global_load_lds(                                  \
                (gas_ptr)(const void*)((src) +                                 \
                    (long long)((h) * 128 + s_ * 64) * K + tc_ * 64),          \
                (las_ptr)(void*)&lds[bs_ +                                     \
                    ((h) * 128 + s_ * 64 + wave * 8) * 64 + lane * 8],         \
                16, 0, 0);                                                     \
        }                                                                      \
    }

// A-fragments for quadrant q of the wave's 128 rows, buffer d: 4 ds_read_b128
#define LDA(d, q)                                                              \
    _Pragma("unroll")                                                          \
    for (int i_ = 0; i_ < 2; ++i_) {                                           \
        _Pragma("unroll")                                                      \
        for (int kk_ = 0; kk_ < 2; ++kk_) {                                    \
            const int row_ = wm + (q) * 32 + i_ * 16 + fr;                     \
            const int sl_  = row_ * 8 + ((kk_ * 4 + quad) ^ (row_ & 7));       \
            fa[i_][kk_] = *(const f16x8*)&As[(d) * 16384 + sl_ * 8];           \
        }                                                                      \
    }

// B-fragments for the wave's 64 cols, buffer d: 8 ds_read_b128 (held 4 phases)
#define LDB(d)                                                                 \
    _Pragma("unroll")                                                          \
    for (int j_ = 0; j_ < 4; ++j_) {                                           \
        _Pragma("unroll")                                                      \
        for (int kk_ = 0; kk_ < 2; ++kk_) {                                    \
            const int row_ = wn + j_ * 16 + fr;                                \
            const int sl_  = row_ * 8 + ((kk_ * 4 + quad) ^ (row_ & 7));       \
            fb[j_][kk_] = *(const f16x8*)&Bs[(d) * 16384 + sl_ * 8];           \
        }                                                                      \
    }

// 16 MFMA = one C-quadrant (32 rows x 64 cols) x K=64, setprio-wrapped (T5)
#define MFMAQ(q)                                                               \
    __builtin_amdgcn_s_setprio(1);                                             \
    _Pragma("unroll")                                                          \
    for (int kk_ = 0; kk_ < 2; ++kk_) {                                        \
        _Pragma("unroll")                                                      \
        for (int i_ = 0; i_ < 2; ++i_) {                                       \
            _Pragma("unroll")                                                  \
            for (int j_ = 0; j_ < 4; ++j_) {                                   \
                acc[(q) * 2 + i_][j_] = __builtin_amdgcn_mfma_f32_16x16x32_f16(\
                    fa[i_][kk_], fb[j_][kk_], acc[(q) * 2 + i_][j_], 0, 0, 0); \
            }                                                                  \
        }                                                                      \
    }                                                                          \
    __builtin_amdgcn_s_setprio(0);

#define SYNC1                                                                  \
    __builtin_amdgcn_s_barrier();                                              \
    asm volatile("s_waitcnt lgkmcnt(0)" ::: "memory");

#define BAR2 __builtin_amdgcn_s_barrier();

    // prologue: A(0) h0,h1; B(0) h0,h1; B(1) h0,h1  (12 loads)
    STG(srcA, As, 0, 0); STG(srcA, As, 0, 1);
    STG(srcB, Bs, 0, 0); STG(srcB, Bs, 0, 1);
    STG(srcB, Bs, 1, 0); STG(srcB, Bs, 1, 1);
    asm volatile("s_waitcnt vmcnt(4)" ::: "memory");  // A(0),B(0) landed; B(1) in flight
    __builtin_amdgcn_s_barrier();

    f16x8 fa[2][2], fb[4][2];

    for (int it = 0; it < NI; ++it) {
        const int t0 = it * 2;
        // ---- ph1: tile t0 (buf0) quad0; B fully read into regs ----
        LDB(0); LDA(0, 0);
        STG(srcA, As, t0 + 1, 0);           // A-buf1 dead since prev ph8
        SYNC1; MFMAQ(0); BAR2;
        // ---- ph2 ----
        LDA(0, 1);
        STG(srcA, As, t0 + 1, 1);
        STG(srcB, Bs, t0 + 2, 0);           // B-buf0 dead after ph1
        SYNC1; MFMAQ(1); BAR2;
        // ---- ph3 ----
        LDA(0, 2);
        STG(srcB, Bs, t0 + 2, 1);
        SYNC1; MFMAQ(2); BAR2;
        // ---- ph4: vmcnt(4) -> A(t0+1),B(t0+1) complete; B(t0+2) stays in flight
        LDA(0, 3);
        SYNC1; MFMAQ(3);
        asm volatile("s_waitcnt vmcnt(4)" ::: "memory");
        BAR2;
        // ---- ph5: tile t0+1 (buf1) quad0 ----
        LDB(1); LDA(1, 0);
        STG(srcA, As, t0 + 2, 0);           // A-buf0 dead after ph4
        SYNC1; MFMAQ(0); BAR2;
        // ---- ph6 ----
        LDA(1, 1);
        STG(srcA, As, t0 + 2, 1);
        STG(srcB, Bs, t0 + 3, 0);           // B-buf1 dead after ph5
        SYNC1; MFMAQ(1); BAR2;
        // ---- ph7 ----
        LDA(1, 2);
        STG(srcB, Bs, t0 + 3, 1);
        SYNC1; MFMAQ(2); BAR2;
        // ---- ph8: vmcnt(4) -> A(t0+2),B(t0+2) complete; B(t0+3) in flight
        LDA(1, 3);
        SYNC1; MFMAQ(3);
        asm volatile("s_waitcnt vmcnt(4)" ::: "memory");
        BAR2;
    }
    // drain stale last-iteration prefetches before the wave can exit
    asm volatile("s_waitcnt vmcnt(0)" ::: "memory");

#undef STG
#undef LDA
#undef LDB
#undef MFMAQ
#undef SYNC1
#undef BAR2

    // epilogue: C/D layout col=lane&15, row=(lane>>4)*4+reg  [m89/m91]
    const int er = quad;
    const int ec = fr;
    #pragma unroll
    for (int j = 0; j < 4; j++) {
        const int col = bn + wn + j * 16 + ec;
        const float bj = bias[col];
        #pragma unroll
        for (int i = 0; i < 8; i++) {
            #pragma unroll
            for (int r = 0; r < 4; r++) {
                const int row = bm + wm + i * 16 + er * 4 + r;
                float v = acc[i][j][r] + bj;
                if (EPI == OP_BIAS_GELU) v = fast_gelu(v);
                Cb[(long long)row * N + col] = f2h(v);
            }
        }
    }
}

// ---------------------------------------------------------------------------
// 128x128 kernel kept for the attention GEMMs: 256^2 tiles would create a
// 1.07-GFLOP single-block tail in scores@v (Keff up to 2048 on one CU) and a
// 2-round tail in the packed-triangle scores grid. Unchanged from baseline.
// ---------------------------------------------------------------------------
template <int EPI, bool CAUSAL_K, bool TRI, bool REVM>
__global__ __launch_bounds__(256, 4) void gemm_bt(
    const unsigned short* __restrict__ A,
    const unsigned short* __restrict__ BT,
    unsigned short* __restrict__ Cw,
    const float* __restrict__ bias0,
    const float* __restrict__ bias1,
    const float* __restrict__ bias2,
    int M, int N, int K,
    long long sA, long long sB, long long sC,
    float scale)
{
    __shared__ __align__(16) unsigned short As[BM * BK];
    __shared__ __align__(16) unsigned short Bs[BN * BK];

    const int tid  = threadIdx.x;
    const int wave = tid >> 6;
    const int lane = tid & 63;

    int bm, bn, z;
    if (TRI) {
        // unrank t -> (i, j), j <= i, t = i(i+1)/2 + j
        const int t = blockIdx.x;
        int i = (int)((sqrtf(8.0f * t + 1.0f) - 1.0f) * 0.5f);
        while ((i + 1) * (i + 2) / 2 <= t) i++;
        while (i * (i + 1) / 2 > t) i--;
        const int j = t - i * (i + 1) / 2;
        bm = i * BM;
        bn = j * BN;
        z  = blockIdx.y;
    } else {
        bm = (REVM ? (gridDim.x - 1 - blockIdx.x) : blockIdx.x) * BM;
        bn = blockIdx.y * BN;
        z  = blockIdx.z;
    }

    const unsigned short* Ab = A  + (long long)z * sA;
    const unsigned short* Bb = BT + (long long)z * sB;
    unsigned short*       Cb = Cw + (long long)z * sC;
    const float* bias = nullptr;
    if (EPI == OP_BIAS || EPI == OP_BIAS_GELU)
        bias = (z == 0) ? bias0 : (z == 1) ? bias1 : bias2;

    const int wm = (wave >> 1) * 64;  // wave's 64x64 quadrant
    const int wn = (wave & 1) * 64;

    f32x4 acc[4][4];
    #pragma unroll
    for (int i = 0; i < 4; i++)
        #pragma unroll
        for (int j = 0; j < 4; j++)
            acc[i][j] = (f32x4){0.f, 0.f, 0.f, 0.f};

    int Keff = K;
    if (CAUSAL_K) {
        int kl = bm + BM;
        Keff = kl < K ? kl : K;
    }

    const int srow = lane >> 3;                          // row within 8-row slab
    const int gchw = ((lane & 7) ^ (srow & 7)) * 8;      // swizzled chunk, halfwords
    const int fr   = lane & 15;
    const int quad = lane >> 4;

    // per-lane global staging pointers; advance by BK per iter
    const unsigned short* pA = Ab + (long long)(bm + wave * 32 + srow) * K + gchw;
    const unsigned short* pB = Bb + (long long)(bn + wave * 32 + srow) * K + gchw;
    const long long rstep = 8ll * K;  // 8 rows between the 4 slabs of a wave

    for (int k0 = 0; k0 < Keff; k0 += BK) {
        #pragma unroll
        for (int s = 0; s < 4; ++s) {
            const int t = wave * 4 + s;
            __builtin_amdgcn_global_load_lds((gas_ptr)(const void*)(pA + s * rstep),
                                             (las_ptr)(void*)&As[t * 512 + lane * 8],
                                             16, 0, 0);
            __builtin_amdgcn_global_load_lds((gas_ptr)(const void*)(pB + s * rstep),
                                             (las_ptr)(void*)&Bs[t * 512 + lane * 8],
                                             16, 0, 0);
        }
        pA += BK;
        pB += BK;
        __syncthreads();  // drains vmcnt -> staged data visible

        #pragma unroll
        for (int kk = 0; kk < 2; ++kk) {
            f16x8 fa[4], fb[4];
            #pragma unroll
            for (int i = 0; i < 4; i++) {
                const int row  = wm + i * 16 + fr;
                const int slot = row * 8 + ((kk * 4 + quad) ^ (fr & 7));
                fa[i] = *(const f16x8*)&As[slot * 8];
            }
            #pragma unroll
            for (int j = 0; j < 4; j++) {
                const int row  = wn + j * 16 + fr;
                const int slot = row * 8 + ((kk * 4 + quad) ^ (fr & 7));
                fb[j] = *(const f16x8*)&Bs[slot * 8];
            }
            #pragma unroll
            for (int i = 0; i < 4; i++)
                #pragma unroll
                for (int j = 0; j < 4; j++)
                    acc[i][j] = __builtin_amdgcn_mfma_f32_16x16x32_f16(
                        fa[i], fb[j], acc[i][j], 0, 0, 0);
        }
        __syncthreads();  // protect LDS before next stage overwrites
    }

    // epilogue: C/D layout col=lane&15, row=(lane>>4)*4+reg  [m89/m91]
    const int er = quad;
    const int ec = fr;
    #pragma unroll
    for (int j = 0; j < 4; j++) {
        const int col = bn + wn + j * 16 + ec;
        float bj = 0.f;
        if (EPI == OP_BIAS || EPI == OP_BIAS_GELU) bj = bias[col];
        #pragma unroll
        for (int i = 0; i < 4; i++) {
            #pragma unroll
            for (int r = 0; r < 4; r++) {
                const int row = bm + wm + i * 16 + er * 4 + r;
                float v = acc[i][j][r];
                if (EPI == OP_BIAS_GELU) {
                    v = fast_gelu(v + bj);
                } else if (EPI == OP_BIAS) {
                    v += bj;
                } else if (EPI == OP_SCALE_MASK) {
                    v *= scale;
                    if (col > row) v = 0.f;
                }
                Cb[(long long)row * N + col] = f2h(v);
            }
        }
    }
}

// fp32 -> fp16 elementwise (n divisible by 1024)
__global__ __launch_bounds__(256) void cvt_f32_f16(
    const float4* __restrict__ in, ushort4* __restrict__ out)
{
    int i = blockIdx.x * 256 + threadIdx.x;
    float4 f = in[i];
    ushort4 o;
    o.x = f2h(f.x); o.y = f2h(f.y); o.z = f2h(f.z); o.w = f2h(f.w);
    out[i] = o;
}

// all six weight matrices: fp32 -> fp16 transposed, one dispatch (z=0..5).
__global__ __launch_bounds__(256) void wprep(
    const float* __restrict__ s0, const float* __restrict__ s1,
    const float* __restrict__ s2, const float* __restrict__ s3,
    const float* __restrict__ s4, const float* __restrict__ s5,
    unsigned short* __restrict__ W1T, unsigned short* __restrict__ W2T)
{
    const int C = 1024;
    const int z = blockIdx.z;
    const float* in = (z == 0) ? s0 : (z == 1) ? s1 : (z == 2) ? s2
                    : (z == 3) ? s3 : (z == 4) ? s4 : s5;
    unsigned short* out = (z < 3) ? (W1T + (long long)z * C * C)
                                  : (W2T + (long long)(z - 3) * C * C);
    __shared__ unsigned short tile[32][33];
    const int bx = blockIdx.x * 32;  // col base
    const int by = blockIdx.y * 32;  // row base
    const int x = threadIdx.x;
    for (int y = threadIdx.y; y < 32; y += 8)
        tile[y][x] = f2h(in[(long long)(by + y) * C + (bx + x)]);
    __syncthreads();
    for (int y = threadIdx.y; y < 32; y += 8)
        out[(long long)(bx + y) * C + (by + x)] = tile[x][y];
}

// wide fp16 transpose: 64x64 tiles, ushort4 (8B) loads AND stores.
// grid (cols/64, rows/64, NB); out[col][row] = in[row][col].
__global__ __launch_bounds__(256) void transpose64_f16(
    const unsigned short* __restrict__ in,
    unsigned short* __restrict__ out,
    int rows, int cols,
    long long sIn, long long sOut)
{
    __shared__ unsigned short tile[64][68];  // stride 68 shorts = 136 B (8B-aligned)
    const unsigned short* ip = in  + (long long)blockIdx.z * sIn;
    unsigned short*       op = out + (long long)blockIdx.z * sOut;
    const int bx = blockIdx.x * 64;  // col base
    const int by = blockIdx.y * 64;  // row base
    const int tid = threadIdx.x;
    const int rsub = tid >> 4;        // 0..15
    const int c4   = (tid & 15) * 4;  // 0,4,..,60
    #pragma unroll
    for (int it = 0; it < 4; it++) {
        const int r = it * 16 + rsub;
        ushort4 v = *(const ushort4*)&ip[(long long)(by + r) * cols + (bx + c4)];
        tile[r][c4]     = v.x;
        tile[r][c4 + 1] = v.y;
        tile[r][c4 + 2] = v.z;
        tile[r][c4 + 3] = v.w;
    }
    __syncthreads();
    #pragma unroll
    for (int it = 0; it < 4; it++) {
        const int cc = it * 16 + rsub;  // out row = in col
        ushort4 v;
        v.x = tile[c4][cc];
        v.y = tile[c4 + 1][cc];
        v.z = tile[c4 + 2][cc];
        v.w = tile[c4 + 3][cc];
        *(ushort4*)&op[(long long)(bx + cc) * rows + (by + c4)] = v;
    }
}

// one 256-thread block per row of 1024; fp16 in, fp32 params, fp32 out
__global__ __launch_bounds__(256) void layernorm_h(
    const unsigned short* __restrict__ X,
    const float* __restrict__ W,
    const float* __restrict__ Bv,
    float* __restrict__ Y)
{
    const int row = blockIdx.x;
    const int tid = threadIdx.x;
    ushort4 u = ((const ushort4*)(X + (long long)row * 1024))[tid];
    float f0 = h2f(u.x), f1 = h2f(u.y), f2 = h2f(u.z), f3 = h2f(u.w);
    float s  = f0 + f1 + f2 + f3;
    float ss = f0 * f0 + f1 * f1 + f2 * f2 + f3 * f3;
    #pragma unroll
    for (int off = 32; off > 0; off >>= 1) {
        s  += __shfl_down(s, off);
        ss += __shfl_down(ss, off);
    }
    __shared__ float red[2][4];
    const int wv = tid >> 6;
    if ((tid & 63) == 0) { red[0][wv] = s; red[1][wv] = ss; }
    __syncthreads();
    float S  = red[0][0] + red[0][1] + red[0][2] + red[0][3];
    float SS = red[1][0] + red[1][1] + red[1][2] + red[1][3];
    float mu  = S * (1.f / 1024.f);
    float var = SS * (1.f / 1024.f) - mu * mu;
    float rs  = rsqrtf(var + 1e-5f);
    float4 w4 = ((const float4*)W)[tid];
    float4 b4 = ((const float4*)Bv)[tid];
    float4 o;
    o.x = (f0 - mu) * rs * w4.x + b4.x;
    o.y = (f1 - mu) * rs * w4.y + b4.y;
    o.z = (f2 - mu) * rs * w4.z + b4.z;
    o.w = (f3 - mu) * rs * w4.w + b4.w;
    ((float4*)(Y + (long long)row * 1024))[tid] = o;
}

extern "C" void kernel_launch(void* const* d_in, const int* in_sizes, int n_in,
                              void* d_out, int out_size, void* d_ws, size_t ws_size,
                              hipStream_t stream)
{
    const int C  = 1024;
    const int T  = 2048;
    const int NB = 8;
    const int MT = NB * T;  // 16384 rows

    const float* x = (const float*)d_in[0];
    const float* W1q = (const float*)d_in[1];
    const float* b1q = (const float*)d_in[2];
    const float* W2q = (const float*)d_in[3];
    const float* b2q = (const float*)d_in[4];
    const float* W1k = (const float*)d_in[5];
    const float* b1k = (const float*)d_in[6];
    const float* W2k = (const float*)d_in[7];
    const float* b2k = (const float*)d_in[8];
    const float* W1v = (const float*)d_in[9];
    const float* b1v = (const float*)d_in[10];
    const float* W2v = (const float*)d_in[11];
    const float* b2v = (const float*)d_in[12];
    const float* lnw = (const float*)d_in[13];
    const float* lnb = (const float*)d_in[14];

    char* wsp = (char*)d_ws;
    auto take = [&](size_t bytes) {
        char* p = wsp;
        wsp += (bytes + 255) & ~(size_t)255;
        return p;
    };

    const size_t MATE = (size_t)MT * C;  // elements per [16384][1024] matrix

    unsigned short* W1T  = (unsigned short*)take((size_t)3 * C * C * 2);
    unsigned short* W2T  = (unsigned short*)take((size_t)3 * C * C * 2);
    unsigned short* xb   = (unsigned short*)take(MATE * 2);
    unsigned short* qkv  = (unsigned short*)take(3 * MATE * 2);  // q,k,v contiguous
    unsigned short* hreg = (unsigned short*)take(3 * MATE * 2);  // h; later scb+opre
    unsigned short* qb   = qkv;
    unsigned short* kb   = qkv + MATE;
    unsigned short* vb   = qkv + 2 * MATE;
    unsigned short* vT   = xb;                               // xb dead after MLP1
    unsigned short* scb  = hreg;                             // 8*T*T = 2*MATE elems
    unsigned short* opre = hreg + (size_t)NB * T * T;        // MATE elems — exact fit

    // x: fp32 -> fp16
    cvt_f32_f16<<<dim3(MT * C / 1024, 1, 1), dim3(256, 1, 1), 0, stream>>>(
        (const float4*)x, (ushort4*)xb);

    // all weights: fp32 -> fp16 transposed, one dispatch
    wprep<<<dim3(C / 32, C / 32, 6), dim3(32, 8, 1), 0, stream>>>(
        W1q, W1k, W1v, W2q, W2k, W2v, W1T, W2T);

    dim3 blk(256, 1, 1);
    dim3 blk512(512, 1, 1);

    // MLP GEMM1 (z = head): h_z = GELU(x @ W1_z + b1_z)  — 8-phase 256^2 kernel
    gemm256<OP_BIAS_GELU><<<dim3(MT / 256, C / 256, 3), blk512, 0, stream>>>(
        xb, W1T, hreg, b1q, b1k, b1v, MT, C, C,
        0, (long long)C * C, (long long)MATE);

    // MLP GEMM2 (z = head): {q,k,v}_z = h_z @ W2_z + b2_z
    gemm256<OP_BIAS><<<dim3(MT / 256, C / 256, 3), blk512, 0, stream>>>(
        hreg, W2T, qkv, b2q, b2k, b2v, MT, C, C,
        (long long)MATE, (long long)C * C, (long long)MATE);

    // vT[b] = v[b]^T ([C][T] per batch) for the scores@v GEMM's BT operand
    transpose64_f16<<<dim3(C / 64, T / 64, NB), blk, 0, stream>>>(
        vb, vT, T, C, (long long)T * C, (long long)T * C);

    // scores = tril(q @ k^T) / sqrt(C*T); packed lower-triangle grid
    float inv_scale = 1.0f / sqrtf((float)C * (float)T);
    gemm_bt<OP_SCALE_MASK, false, true, false><<<dim3(136, NB, 1), blk, 0, stream>>>(
        qb, kb, scb, nullptr, nullptr, nullptr, T, T, C,
        (long long)T * C, (long long)T * C, (long long)T * T, inv_scale);

    // out_pre = scores @ v (K limited to bm+BM); longest-K blocks first (LPT)
    gemm_bt<OP_NONE, true, false, true><<<dim3(T / BM, C / BN, NB), blk, 0, stream>>>(
        scb, vT, opre, nullptr, nullptr, nullptr, T, C, T,
        (long long)T * T, (long long)T * C, (long long)T * C, 1.f);

    layernorm_h<<<dim3(MT, 1, 1), dim3(256, 1, 1), 0, stream>>>(
        opre, lnw, lnb, (float*)d_out);
}

// Round 2
// 554.644 us; speedup vs baseline: 1.0542x; 1.0542x over previous
//
#include <hip/hip_runtime.h>
#include <math.h>

#define BM 128
#define BN 128
#define BK 64

typedef _Float16 f16x8 __attribute__((ext_vector_type(8)));
typedef __attribute__((ext_vector_type(4))) float f32x4;

typedef const __attribute__((address_space(1))) void* gas_ptr;
typedef __attribute__((address_space(3))) void* las_ptr;

enum { OP_NONE = 0, OP_BIAS_GELU = 1, OP_BIAS = 2, OP_SCALE_MASK = 3 };

__device__ __forceinline__ unsigned short f2h(float f) {
    _Float16 h = (_Float16)f;  // RTNE
    unsigned short u;
    __builtin_memcpy(&u, &h, 2);
    return u;
}
__device__ __forceinline__ float h2f(unsigned short u) {
    _Float16 h;
    __builtin_memcpy(&h, &u, 2);
    return (float)h;
}

// tanh-form GELU via sigmoid: ~7 VALU instrs vs ~50 for libm erff.
// R6/R7 confirmed: absmax stays 0.03125 with this approximation.
__device__ __forceinline__ float fast_gelu(float x) {
    float x2 = x * x;
    float p  = x * (-1.5957691216f - 0.0713548164f * x2);  // = -2u
    float t  = __expf(p);                                  // e^{-2u}
    return x * __builtin_amdgcn_rcpf(1.0f + t);            // x * sigma(2u)
}

// ---------------------------------------------------------------------------
// 256x256-tile 8-phase GEMM (m201 template port) for the MLP GEMMs.
// 8 waves (2M x 4N), BK=64, 128 KiB LDS double-buffer, per-wave 128x64 out.
//
// R2 fixes vs R1 (which ran 136 us / MfmaUtil 31%):
//  - exactly 1 half-tile STG (2 global_load_lds) per phase (was clumped 4/0)
//  - NO blanket lgkmcnt(0): ds_reads are compiler-visible, so the compiler
//    emits fine-grained lgkmcnt(N) per fragment -> first MFMAs start while
//    later ds_reads drain (cross-wave LDS/MFMA overlap)
//  - kk-major fragment loads (kk=0 frags arrive first, consumed first)
//  - j-innermost epilogue: a C-row's 4x32B slices are 4 consecutive stores
//    (R1 had 2x HBM write amplification from partial-line evictions)
//
// vmcnt ledger (2 loads per STG, in-order completion):
//  prologue: A0h0,A0h1,B0h0,B0h1,B1h0,B1h1 (12) -> vmcnt(4): A0,B0 landed,
//            B1 (4 loads) in flight.
//  steady iter (tiles t=2it, t+1): stages ph1:A(t+1)h0 ph2:A(t+1)h1
//    ph3:B(t+2)h0 ph4:B(t+2)h1 ph5:A(t+2)h0 ph6:A(t+2)h1 ph7:B(t+3)h0
//    ph8:B(t+3)h1.
//  ph4: outstanding 12 = [B(t+1)x4, A(t+1)x4, B(t+2)x4]; vmcnt(4) completes
//       B(t+1)+A(t+1) = tile t+1 (read ph5-8). Leaves B(t+2)x4.
//  ph8: outstanding 12 = [B(t+2)x4, A(t+2)x4, B(t+3)x4]; vmcnt(4) completes
//       tile t+2 (read next ph1-4). Leaves B(t+3)x4 = steady precondition.
// Buffer-overwrite safety: a phase's ds_reads are consumed by its own MFMAs
// (compiler lgkm waits) before that phase's closing barrier, so staging into
// a region >= 1 full phase after its last read is race-free:
//  B-buf read ph1/ph5, staged ph3+/ph7+; A-buf read through ph4/ph8, staged
//  ph5+/ph1+(next). Requires M,N % 256 == 0, K % 128 == 0.
// ---------------------------------------------------------------------------
template <int EPI>
__global__ __launch_bounds__(512, 2) void gemm256(
    const unsigned short* __restrict__ A,
    const unsigned short* __restrict__ BT,
    unsigned short* __restrict__ Cw,
    const float* __restrict__ bias0,
    const float* __restrict__ bias1,
    const float* __restrict__ bias2,
    int M, int N, int K,
    long long sA, long long sB, long long sC)
{
    __shared__ __align__(16) unsigned short As[2 * 256 * 64];  // 64 KiB
    __shared__ __align__(16) unsigned short Bs[2 * 256 * 64];  // 64 KiB

    const int tid  = threadIdx.x;
    const int wave = tid >> 6;
    const int lane = tid & 63;

    const int bm = blockIdx.x * 256;
    const int bn = blockIdx.y * 256;
    const int z  = blockIdx.z;

    const unsigned short* Ab = A  + (long long)z * sA;
    const unsigned short* Bb = BT + (long long)z * sB;
    unsigned short*       Cb = Cw + (long long)z * sC;
    const float* bias = (z == 0) ? bias0 : (z == 1) ? bias1 : bias2;

    const int wm = (wave >> 2) * 128;  // 2 M-wave groups
    const int wn = (wave & 3) * 64;    // 4 N-wave groups

    const int srow = lane >> 3;              // 0..7: row within 8-row slab
    const int swzc = (lane & 7) ^ srow;      // pre-swizzled global chunk
    const int fr   = lane & 15;
    const int quad = lane >> 4;

    // per-lane staging sources (row = base + wave*8 + srow, col = swzc*8)
    const unsigned short* srcA = Ab + (long long)(bm + wave * 8 + srow) * K + swzc * 8;
    const unsigned short* srcB = Bb + (long long)(bn + wave * 8 + srow) * K + swzc * 8;

    const int NT = K >> 6;   // 64-wide K-tiles; even by contract
    const int NI = NT >> 1;

    f32x4 acc[8][4];
    #pragma unroll
    for (int i = 0; i < 8; i++)
        #pragma unroll
        for (int j = 0; j < 4; j++)
            acc[i][j] = (f32x4){0.f, 0.f, 0.f, 0.f};

// stage one half-tile (128 rows x 64 cols) of tile t, half h: 2 loads/thread.
// LDS dest is linear (wave-uniform base + lane*16); source pre-swizzled.
// t >= NT clamps the k-column to tile (t&1) (same buffer parity; value dead).
#define STG(src, lds, t, h)                                                    \
    {                                                                          \
        const int tc_ = ((t) < NT) ? (t) : ((t) & 1);                          \
        const int bs_ = ((t) & 1) * 16384;                                     \
        _Pragma("unroll")                                                      \
        for (int s_ = 0; s_ < 2; ++s_) {                                       \
            __builtin_amdgcn_global_load_lds(                                  \
                (gas_ptr)(const void*)((src) +                                 \
                    (long long)((h) * 128 + s_ * 64) * K + tc_ * 64),          \
                (las_ptr)(void*)&lds[bs_ +                                     \
                    ((h) * 128 + s_ * 64 + wave * 8) * 64 + lane * 8],         \
                16, 0, 0);                                                     \
        }                                                                      \
    }

// A-fragments for quadrant q of the wave's 128 rows, buffer d: 4 ds_read_b128
// kk-major: kk=0 fragments issue (and complete) first.
#define LDA(d, q)                                                              \
    _Pragma("unroll")                                                          \
    for (int kk_ = 0; kk_ < 2; ++kk_) {                                        \
        _Pragma("unroll")                                                      \
        for (int i_ = 0; i_ < 2; ++i_) {                                       \
            const int row_ = wm + (q) * 32 + i_ * 16 + fr;                     \
            const int sl_  = row_ * 8 + ((kk_ * 4 + quad) ^ (row_ & 7));       \
            fa[i_][kk_] = *(const f16x8*)&As[(d) * 16384 + sl_ * 8];           \
        }                                                                      \
    }

// B-fragments for the wave's 64 cols, buffer d: 8 ds_read_b128 (held 4 phases)
#define LDB(d)                                                                 \
    _Pragma("unroll")                                                          \
    for (int kk_ = 0; kk_ < 2; ++kk_) {                                        \
        _Pragma("unroll")                                                      \
        for (int j_ = 0; j_ < 4; ++j_) {                                       \
            const int row_ = wn + j_ * 16 + fr;                                \
            const int sl_  = row_ * 8 + ((kk_ * 4 + quad) ^ (row_ & 7));       \
            fb[j_][kk_] = *(const f16x8*)&Bs[(d) * 16384 + sl_ * 8];           \
        }                                                                      \
    }

// 16 MFMA = one C-quadrant (32 rows x 64 cols) x K=64, setprio-wrapped (T5)
#define MFMAQ(q)                                                               \
    __builtin_amdgcn_s_setprio(1);                                             \
    _Pragma("unroll")                                                          \
    for (int kk_ = 0; kk_ < 2; ++kk_) {                                        \
        _Pragma("unroll")                                                      \
        for (int i_ = 0; i_ < 2; ++i_) {                                       \
            _Pragma("unroll")                                                  \
            for (int j_ = 0; j_ < 4; ++j_) {                                   \
                acc[(q) * 2 + i_][j_] = __builtin_amdgcn_mfma_f32_16x16x32_f16(\
                    fa[i_][kk_], fb[j_][kk_], acc[(q) * 2 + i_][j_], 0, 0, 0); \
            }                                                                  \
        }                                                                      \
    }                                                                          \
    __builtin_amdgcn_s_setprio(0);

#define BARA __builtin_amdgcn_s_barrier();
#define BARB __builtin_amdgcn_s_barrier();

    // prologue: A(0) h0,h1; B(0) h0,h1; B(1) h0,h1  (12 loads)
    STG(srcA, As, 0, 0); STG(srcA, As, 0, 1);
    STG(srcB, Bs, 0, 0); STG(srcB, Bs, 0, 1);
    STG(srcB, Bs, 1, 0); STG(srcB, Bs, 1, 1);
    asm volatile("s_waitcnt vmcnt(4)" ::: "memory");  // A(0),B(0) landed; B(1) in flight
    __builtin_amdgcn_s_barrier();

    f16x8 fa[2][2], fb[4][2];

    for (int it = 0; it < NI; ++it) {
        const int t0 = it * 2;
        // ---- ph1: tile t0 (buf0) quad0; B read into regs (held 4 phases) ----
        LDB(0); LDA(0, 0);
        STG(srcA, As, t0 + 1, 0);
        BARA; MFMAQ(0); BARB;
        // ---- ph2 ----
        LDA(0, 1);
        STG(srcA, As, t0 + 1, 1);
        BARA; MFMAQ(1); BARB;
        // ---- ph3 ----
        LDA(0, 2);
        STG(srcB, Bs, t0 + 2, 0);
        BARA; MFMAQ(2); BARB;
        // ---- ph4: vmcnt(4) -> tile t0+1 complete; B(t0+2) stays in flight
        LDA(0, 3);
        STG(srcB, Bs, t0 + 2, 1);
        BARA; MFMAQ(3);
        asm volatile("s_waitcnt vmcnt(4)" ::: "memory");
        BARB;
        // ---- ph5: tile t0+1 (buf1) quad0 ----
        LDB(1); LDA(1, 0);
        STG(srcA, As, t0 + 2, 0);
        BARA; MFMAQ(0); BARB;
        // ---- ph6 ----
        LDA(1, 1);
        STG(srcA, As, t0 + 2, 1);
        BARA; MFMAQ(1); BARB;
        // ---- ph7 ----
        LDA(1, 2);
        STG(srcB, Bs, t0 + 3, 0);
        BARA; MFMAQ(2); BARB;
        // ---- ph8: vmcnt(4) -> tile t0+2 complete; B(t0+3) in flight
        LDA(1, 3);
        STG(srcB, Bs, t0 + 3, 1);
        BARA; MFMAQ(3);
        asm volatile("s_waitcnt vmcnt(4)" ::: "memory");
        BARB;
    }
    // drain stale last-iteration prefetches before the wave can exit
    asm volatile("s_waitcnt vmcnt(0)" ::: "memory");

#undef STG
#undef LDA
#undef LDB
#undef MFMAQ
#undef BARA
#undef BARB

    // epilogue: C/D layout col=lane&15, row=(lane>>4)*4+reg  [m89/m91]
    // j INNERMOST: each row's 4x32B slices are consecutive stores -> L2 lines
    // (128B = one wave's 64-col stripe) fully dirtied immediately (R1 had 2x
    // write amplification with j outermost).
    const int er = quad;
    const int ec = fr;
    float bj[4];
    #pragma unroll
    for (int j = 0; j < 4; j++) bj[j] = bias[bn + wn + j * 16 + ec];
    #pragma unroll
    for (int i = 0; i < 8; i++) {
        #pragma unroll
        for (int r = 0; r < 4; r++) {
            const int row = bm + wm + i * 16 + er * 4 + r;
            #pragma unroll
            for (int j = 0; j < 4; j++) {
                float v = acc[i][j][r] + bj[j];
                if (EPI == OP_BIAS_GELU) v = fast_gelu(v);
                Cb[(long long)row * N + (bn + wn + j * 16 + ec)] = f2h(v);
            }
        }
    }
}

// ---------------------------------------------------------------------------
// 128x128 kernel kept for the attention GEMMs: 256^2 tiles would create a
// 1.07-GFLOP single-block tail in scores@v (Keff up to 2048 on one CU) and a
// 2-round tail in the packed-triangle scores grid. Unchanged from baseline.
// ---------------------------------------------------------------------------
template <int EPI, bool CAUSAL_K, bool TRI, bool REVM>
__global__ __launch_bounds__(256, 4) void gemm_bt(
    const unsigned short* __restrict__ A,
    const unsigned short* __restrict__ BT,
    unsigned short* __restrict__ Cw,
    const float* __restrict__ bias0,
    const float* __restrict__ bias1,
    const float* __restrict__ bias2,
    int M, int N, int K,
    long long sA, long long sB, long long sC,
    float scale)
{
    __shared__ __align__(16) unsigned short As[BM * BK];
    __shared__ __align__(16) unsigned short Bs[BN * BK];

    const int tid  = threadIdx.x;
    const int wave = tid >> 6;
    const int lane = tid & 63;

    int bm, bn, z;
    if (TRI) {
        // unrank t -> (i, j), j <= i, t = i(i+1)/2 + j
        const int t = blockIdx.x;
        int i = (int)((sqrtf(8.0f * t + 1.0f) - 1.0f) * 0.5f);
        while ((i + 1) * (i + 2) / 2 <= t) i++;
        while (i * (i + 1) / 2 > t) i--;
        const int j = t - i * (i + 1) / 2;
        bm = i * BM;
        bn = j * BN;
        z  = blockIdx.y;
    } else {
        bm = (REVM ? (gridDim.x - 1 - blockIdx.x) : blockIdx.x) * BM;
        bn = blockIdx.y * BN;
        z  = blockIdx.z;
    }

    const unsigned short* Ab = A  + (long long)z * sA;
    const unsigned short* Bb = BT + (long long)z * sB;
    unsigned short*       Cb = Cw + (long long)z * sC;
    const float* bias = nullptr;
    if (EPI == OP_BIAS || EPI == OP_BIAS_GELU)
        bias = (z == 0) ? bias0 : (z == 1) ? bias1 : bias2;

    const int wm = (wave >> 1) * 64;  // wave's 64x64 quadrant
    const int wn = (wave & 1) * 64;

    f32x4 acc[4][4];
    #pragma unroll
    for (int i = 0; i < 4; i++)
        #pragma unroll
        for (int j = 0; j < 4; j++)
            acc[i][j] = (f32x4){0.f, 0.f, 0.f, 0.f};

    int Keff = K;
    if (CAUSAL_K) {
        int kl = bm + BM;
        Keff = kl < K ? kl : K;
    }

    const int srow = lane >> 3;                          // row within 8-row slab
    const int gchw = ((lane & 7) ^ (srow & 7)) * 8;      // swizzled chunk, halfwords
    const int fr   = lane & 15;
    const int quad = lane >> 4;

    // per-lane global staging pointers; advance by BK per iter
    const unsigned short* pA = Ab + (long long)(bm + wave * 32 + srow) * K + gchw;
    const unsigned short* pB = Bb + (long long)(bn + wave * 32 + srow) * K + gchw;
    const long long rstep = 8ll * K;  // 8 rows between the 4 slabs of a wave

    for (int k0 = 0; k0 < Keff; k0 += BK) {
        #pragma unroll
        for (int s = 0; s < 4; ++s) {
            const int t = wave * 4 + s;
            __builtin_amdgcn_global_load_lds((gas_ptr)(const void*)(pA + s * rstep),
                                             (las_ptr)(void*)&As[t * 512 + lane * 8],
                                             16, 0, 0);
            __builtin_amdgcn_global_load_lds((gas_ptr)(const void*)(pB + s * rstep),
                                             (las_ptr)(void*)&Bs[t * 512 + lane * 8],
                                             16, 0, 0);
        }
        pA += BK;
        pB += BK;
        __syncthreads();  // drains vmcnt -> staged data visible

        #pragma unroll
        for (int kk = 0; kk < 2; ++kk) {
            f16x8 fa[4], fb[4];
            #pragma unroll
            for (int i = 0; i < 4; i++) {
                const int row  = wm + i * 16 + fr;
                const int slot = row * 8 + ((kk * 4 + quad) ^ (fr & 7));
                fa[i] = *(const f16x8*)&As[slot * 8];
            }
            #pragma unroll
            for (int j = 0; j < 4; j++) {
                const int row  = wn + j * 16 + fr;
                const int slot = row * 8 + ((kk * 4 + quad) ^ (fr & 7));
                fb[j] = *(const f16x8*)&Bs[slot * 8];
            }
            #pragma unroll
            for (int i = 0; i < 4; i++)
                #pragma unroll
                for (int j = 0; j < 4; j++)
                    acc[i][j] = __builtin_amdgcn_mfma_f32_16x16x32_f16(
                        fa[i], fb[j], acc[i][j], 0, 0, 0);
        }
        __syncthreads();  // protect LDS before next stage overwrites
    }

    // epilogue: C/D layout col=lane&15, row=(lane>>4)*4+reg  [m89/m91]
    const int er = quad;
    const int ec = fr;
    #pragma unroll
    for (int j = 0; j < 4; j++) {
        const int col = bn + wn + j * 16 + ec;
        float bj = 0.f;
        if (EPI == OP_BIAS || EPI == OP_BIAS_GELU) bj = bias[col];
        #pragma unroll
        for (int i = 0; i < 4; i++) {
            #pragma unroll
            for (int r = 0; r < 4; r++) {
                const int row = bm + wm + i * 16 + er * 4 + r;
                float v = acc[i][j][r];
                if (EPI == OP_BIAS_GELU) {
                    v = fast_gelu(v + bj);
                } else if (EPI == OP_BIAS) {
                    v += bj;
                } else if (EPI == OP_SCALE_MASK) {
                    v *= scale;
                    if (col > row) v = 0.f;
                }
                Cb[(long long)row * N + col] = f2h(v);
            }
        }
    }
}

// fp32 -> fp16 elementwise (n divisible by 1024)
__global__ __launch_bounds__(256) void cvt_f32_f16(
    const float4* __restrict__ in, ushort4* __restrict__ out)
{
    int i = blockIdx.x * 256 + threadIdx.x;
    float4 f = in[i];
    ushort4 o;
    o.x = f2h(f.x); o.y = f2h(f.y); o.z = f2h(f.z); o.w = f2h(f.w);
    out[i] = o;
}

// all six weight matrices: fp32 -> fp16 transposed, one dispatch (z=0..5).
__global__ __launch_bounds__(256) void wprep(
    const float* __restrict__ s0, const float* __restrict__ s1,
    const float* __restrict__ s2, const float* __restrict__ s3,
    const float* __restrict__ s4, const float* __restrict__ s5,
    unsigned short* __restrict__ W1T, unsigned short* __restrict__ W2T)
{
    const int C = 1024;
    const int z = blockIdx.z;
    const float* in = (z == 0) ? s0 : (z == 1) ? s1 : (z == 2) ? s2
                    : (z == 3) ? s3 : (z == 4) ? s4 : s5;
    unsigned short* out = (z < 3) ? (W1T + (long long)z * C * C)
                                  : (W2T + (long long)(z - 3) * C * C);
    __shared__ unsigned short tile[32][33];
    const int bx = blockIdx.x * 32;  // col base
    const int by = blockIdx.y * 32;  // row base
    const int x = threadIdx.x;
    for (int y = threadIdx.y; y < 32; y += 8)
        tile[y][x] = f2h(in[(long long)(by + y) * C + (bx + x)]);
    __syncthreads();
    for (int y = threadIdx.y; y < 32; y += 8)
        out[(long long)(bx + y) * C + (by + x)] = tile[x][y];
}

// wide fp16 transpose: 64x64 tiles, ushort4 (8B) loads AND stores.
// grid (cols/64, rows/64, NB); out[col][row] = in[row][col].
__global__ __launch_bounds__(256) void transpose64_f16(
    const unsigned short* __restrict__ in,
    unsigned short* __restrict__ out,
    int rows, int cols,
    long long sIn, long long sOut)
{
    __shared__ unsigned short tile[64][68];  // stride 68 shorts = 136 B (8B-aligned)
    const unsigned short* ip = in  + (long long)blockIdx.z * sIn;
    unsigned short*       op = out + (long long)blockIdx.z * sOut;
    const int bx = blockIdx.x * 64;  // col base
    const int by = blockIdx.y * 64;  // row base
    const int tid = threadIdx.x;
    const int rsub = tid >> 4;        // 0..15
    const int c4   = (tid & 15) * 4;  // 0,4,..,60
    #pragma unroll
    for (int it = 0; it < 4; it++) {
        const int r = it * 16 + rsub;
        ushort4 v = *(const ushort4*)&ip[(long long)(by + r) * cols + (bx + c4)];
        tile[r][c4]     = v.x;
        tile[r][c4 + 1] = v.y;
        tile[r][c4 + 2] = v.z;
        tile[r][c4 + 3] = v.w;
    }
    __syncthreads();
    #pragma unroll
    for (int it = 0; it < 4; it++) {
        const int cc = it * 16 + rsub;  // out row = in col
        ushort4 v;
        v.x = tile[c4][cc];
        v.y = tile[c4 + 1][cc];
        v.z = tile[c4 + 2][cc];
        v.w = tile[c4 + 3][cc];
        *(ushort4*)&op[(long long)(bx + cc) * rows + (by + c4)] = v;
    }
}

// one 256-thread block per row of 1024; fp16 in, fp32 params, fp32 out
__global__ __launch_bounds__(256) void layernorm_h(
    const unsigned short* __restrict__ X,
    const float* __restrict__ W,
    const float* __restrict__ Bv,
    float* __restrict__ Y)
{
    const int row = blockIdx.x;
    const int tid = threadIdx.x;
    ushort4 u = ((const ushort4*)(X + (long long)row * 1024))[tid];
    float f0 = h2f(u.x), f1 = h2f(u.y), f2 = h2f(u.z), f3 = h2f(u.w);
    float s  = f0 + f1 + f2 + f3;
    float ss = f0 * f0 + f1 * f1 + f2 * f2 + f3 * f3;
    #pragma unroll
    for (int off = 32; off > 0; off >>= 1) {
        s  += __shfl_down(s, off);
        ss += __shfl_down(ss, off);
    }
    __shared__ float red[2][4];
    const int wv = tid >> 6;
    if ((tid & 63) == 0) { red[0][wv] = s; red[1][wv] = ss; }
    __syncthreads();
    float S  = red[0][0] + red[0][1] + red[0][2] + red[0][3];
    float SS = red[1][0] + red[1][1] + red[1][2] + red[1][3];
    float mu  = S * (1.f / 1024.f);
    float var = SS * (1.f / 1024.f) - mu * mu;
    float rs  = rsqrtf(var + 1e-5f);
    float4 w4 = ((const float4*)W)[tid];
    float4 b4 = ((const float4*)Bv)[tid];
    float4 o;
    o.x = (f0 - mu) * rs * w4.x + b4.x;
    o.y = (f1 - mu) * rs * w4.y + b4.y;
    o.z = (f2 - mu) * rs * w4.z + b4.z;
    o.w = (f3 - mu) * rs * w4.w + b4.w;
    ((float4*)(Y + (long long)row * 1024))[tid] = o;
}

extern "C" void kernel_launch(void* const* d_in, const int* in_sizes, int n_in,
                              void* d_out, int out_size, void* d_ws, size_t ws_size,
                              hipStream_t stream)
{
    const int C  = 1024;
    const int T  = 2048;
    const int NB = 8;
    const int MT = NB * T;  // 16384 rows

    const float* x = (const float*)d_in[0];
    const float* W1q = (const float*)d_in[1];
    const float* b1q = (const float*)d_in[2];
    const float* W2q = (const float*)d_in[3];
    const float* b2q = (const float*)d_in[4];
    const float* W1k = (const float*)d_in[5];
    const float* b1k = (const float*)d_in[6];
    const float* W2k = (const float*)d_in[7];
    const float* b2k = (const float*)d_in[8];
    const float* W1v = (const float*)d_in[9];
    const float* b1v = (const float*)d_in[10];
    const float* W2v = (const float*)d_in[11];
    const float* b2v = (const float*)d_in[12];
    const float* lnw = (const float*)d_in[13];
    const float* lnb = (const float*)d_in[14];

    char* wsp = (char*)d_ws;
    auto take = [&](size_t bytes) {
        char* p = wsp;
        wsp += (bytes + 255) & ~(size_t)255;
        return p;
    };

    const size_t MATE = (size_t)MT * C;  // elements per [16384][1024] matrix

    unsigned short* W1T  = (unsigned short*)take((size_t)3 * C * C * 2);
    unsigned short* W2T  = (unsigned short*)take((size_t)3 * C * C * 2);
    unsigned short* xb   = (unsigned short*)take(MATE * 2);
    unsigned short* qkv  = (unsigned short*)take(3 * MATE * 2);  // q,k,v contiguous
    unsigned short* hreg = (unsigned short*)take(3 * MATE * 2);  // h; later scb+opre
    unsigned short* qb   = qkv;
    unsigned short* kb   = qkv + MATE;
    unsigned short* vb   = qkv + 2 * MATE;
    unsigned short* vT   = xb;                               // xb dead after MLP1
    unsigned short* scb  = hreg;                             // 8*T*T = 2*MATE elems
    unsigned short* opre = hreg + (size_t)NB * T * T;        // MATE elems — exact fit

    // x: fp32 -> fp16
    cvt_f32_f16<<<dim3(MT * C / 1024, 1, 1), dim3(256, 1, 1), 0, stream>>>(
        (const float4*)x, (ushort4*)xb);

    // all weights: fp32 -> fp16 transposed, one dispatch
    wprep<<<dim3(C / 32, C / 32, 6), dim3(32, 8, 1), 0, stream>>>(
        W1q, W1k, W1v, W2q, W2k, W2v, W1T, W2T);

    dim3 blk(256, 1, 1);
    dim3 blk512(512, 1, 1);

    // MLP GEMM1 (z = head): h_z = GELU(x @ W1_z + b1_z)  — 8-phase 256^2 kernel
    gemm256<OP_BIAS_GELU><<<dim3(MT / 256, C / 256, 3), blk512, 0, stream>>>(
        xb, W1T, hreg, b1q, b1k, b1v, MT, C, C,
        0, (long long)C * C, (long long)MATE);

    // MLP GEMM2 (z = head): {q,k,v}_z = h_z @ W2_z + b2_z
    gemm256<OP_BIAS><<<dim3(MT / 256, C / 256, 3), blk512, 0, stream>>>(
        hreg, W2T, qkv, b2q, b2k, b2v, MT, C, C,
        (long long)MATE, (long long)C * C, (long long)MATE);

    // vT[b] = v[b]^T ([C][T] per batch) for the scores@v GEMM's BT operand
    transpose64_f16<<<dim3(C / 64, T / 64, NB), blk, 0, stream>>>(
        vb, vT, T, C, (long long)T * C, (long long)T * C);

    // scores = tril(q @ k^T) / sqrt(C*T); packed lower-triangle grid
    float inv_scale = 1.0f / sqrtf((float)C * (float)T);
    gemm_bt<OP_SCALE_MASK, false, true, false><<<dim3(136, NB, 1), blk, 0, stream>>>(
        qb, kb, scb, nullptr, nullptr, nullptr, T, T, C,
        (long long)T * C, (long long)T * C, (long long)T * T, inv_scale);

    // out_pre = scores @ v (K limited to bm+BM); longest-K blocks first (LPT)
    gemm_bt<OP_NONE, true, false, true><<<dim3(T / BM, C / BN, NB), blk, 0, stream>>>(
        scb, vT, opre, nullptr, nullptr, nullptr, T, C, T,
        (long long)T * T, (long long)T * C, (long long)T * C, 1.f);

    layernorm_h<<<dim3(MT, 1, 1), dim3(256, 1, 1), 0, stream>>>(
        opre, lnw, lnb, (float*)d_out);
}